// Round 5
// baseline (208.815 us; speedup 1.0000x reference)
//
#include <hip/hip_runtime.h>
#include <hip/hip_bf16.h>
#include <stdint.h>

typedef __attribute__((ext_vector_type(8))) short bf16x8;
typedef __attribute__((ext_vector_type(4))) float f32x4;

__device__ __forceinline__ unsigned short f2bf(float f) {
    union { float f; unsigned u; } v; v.f = f;
    unsigned u = v.u;
    u += 0x7fff + ((u >> 16) & 1);   // round-to-nearest-even
    return (unsigned short)(u >> 16);
}

// ---------------------------------------------------------------------------
// prep: blocks [0, nbBin): binner (slot claim per feature).
//       blocks [nbBin, nbBin+nbW): convert W0..W3 fp32 -> bf16 into wsW.
// ---------------------------------------------------------------------------
__global__ __launch_bounds__(256) void prep(
    const int* __restrict__ FI, const int* __restrict__ wptr,
    int* __restrict__ cnt, int* __restrict__ slots,
    const float* __restrict__ W0, const float* __restrict__ W1,
    const float* __restrict__ W2, const float* __restrict__ W3,
    unsigned short* __restrict__ wsW,
    int NF, int HW, int wsz, int nbBin)
{
    int blk = blockIdx.x;
    if (blk < nbBin) {
        int i = blk * 256 + threadIdx.x;
        if (i >= NF) return;
        int Wd = *wptr;
        int b = FI[(size_t)i * 3];
        int h = FI[(size_t)i * 3 + 1];
        int w = FI[(size_t)i * 3 + 2];
        int gc = b * HW + h * Wd + w;
        int slot = atomicAdd(&cnt[gc], 1);
        if (slot < 16) slots[(size_t)gc * 16 + slot] = i;
    } else {
        int idx = ((blk - nbBin) * 256 + threadIdx.x) * 4;
        if (idx >= 4 * wsz) return;
        int l = idx / wsz, off = idx - l * wsz;
        const float* Ws = (l == 0) ? W0 : (l == 1) ? W1 : (l == 2) ? W2 : W3;
        float4 v = *(const float4*)(Ws + off);
        ushort4 o; o.x = f2bf(v.x); o.y = f2bf(v.y); o.z = f2bf(v.z); o.w = f2bf(v.w);
        *(ushort4*)(wsW + (size_t)l * wsz + off) = o;
    }
}

// ---------------------------------------------------------------------------
// gather_mlp: blocks [0, nbM): fused 4-layer MLP.
//             blocks [nbM, nbM+nbG): cell gather, 16 cells per wave.
// Round-5 change: multi-group ILP. Each wave owns 16 consecutive cells
// (4 groups x 4). ALL metadata is hoisted: one coalesced cnt load (16 ints)
// + four independent coalesced slots loads (64 ints each). The 8 half-wave
// passes then depend only on pre-loaded registers, so FV-load chains from
// different groups overlap (memory-level parallelism per wave ~4x round 4).
// Access granularity unchanged from round 4 (512B-contiguous FV loads,
// 256B full-line Abuf stores). shfl discipline unchanged: pass loop bounds
// are wave-uniform (max of the two halves' counts, computed by all lanes
// from the broadcast cv register), so every __shfl has all 64 lanes active.
// ---------------------------------------------------------------------------
__global__ __launch_bounds__(256) void gather_mlp(
    // mlp args
    const float* __restrict__ Qf, const unsigned short* __restrict__ Wb,
    const float* __restrict__ b0p, const float* __restrict__ b1p,
    const float* __restrict__ b2p, const float* __restrict__ b3p,
    unsigned short* __restrict__ outQB, int M, int wsz,
    // gather args
    const float* __restrict__ FV, const int* __restrict__ cnt,
    const int* __restrict__ slots, unsigned short* __restrict__ Abuf, int NC,
    int nbM, int nbG)
{
    __shared__ unsigned short At[16 * 264];
    const int tid = threadIdx.x;
    const int wid = tid >> 6, lane = tid & 63, quad = lane >> 4, l16 = lane & 15;

    if (blockIdx.x >= nbM) {
        // ---------- gather: 16 cells/wave, metadata hoisted, 8 passes ----------
        const int hl  = lane & 31;      // half-lane
        const int hid = lane >> 5;      // which half of the wave
        const int wg = (blockIdx.x - nbM) * 4 + wid;
        const int nw = nbG * 4;
        for (int cb16 = wg * 16; cb16 < NC; cb16 += nw * 16) {
            // --- hoisted metadata: 5 independent coalesced loads ---
            int cv  = cnt[cb16 + l16];                        // 16 cells' counts
            int sl0 = slots[(size_t)cb16 * 16 +   0 + lane];  // group 0: 64 ints
            int sl1 = slots[(size_t)cb16 * 16 +  64 + lane];  // group 1
            int sl2 = slots[(size_t)cb16 * 16 + 128 + lane];  // group 2
            int sl3 = slots[(size_t)cb16 * 16 + 192 + lane];  // group 3
            #pragma unroll
            for (int g = 0; g < 4; ++g) {
                int sl = (g == 0) ? sl0 : (g == 1) ? sl1 : (g == 2) ? sl2 : sl3;
                #pragma unroll
                for (int i = 0; i < 2; ++i) {
                    int j = i * 2 + hid;              // this half's cell within group
                    int c = cb16 + g * 4 + j;
                    // wave-uniform counts via broadcast register (all lanes)
                    int nA = __shfl(cv, g * 4 + i * 2);     if (nA > 16) nA = 16;
                    int nB = __shfl(cv, g * 4 + i * 2 + 1); if (nB > 16) nB = 16;
                    int n    = hid ? nB : nA;               // own trip count
                    int nmax = nA > nB ? nA : nB;           // wave-uniform bound
                    float4 a0 = make_float4(0.f, 0.f, 0.f, 0.f);
                    float4 a1 = a0;
                    for (int s = 0; s < nmax; ++s) {
                        int f = __shfl(sl, j * 16 + s);     // ALL lanes active
                        if (s < n) {
                            const float* src = FV + (size_t)f * 256 + hl * 4;
                            float4 v0 = *(const float4*)(src);         // cols hl*4
                            float4 v1 = *(const float4*)(src + 128);   // cols 128+hl*4
                            a0.x += v0.x; a0.y += v0.y; a0.z += v0.z; a0.w += v0.w;
                            a1.x += v1.x; a1.y += v1.y; a1.z += v1.z; a1.w += v1.w;
                        }
                    }
                    ushort4 o0, o1;
                    o0.x = f2bf(a0.x); o0.y = f2bf(a0.y); o0.z = f2bf(a0.z); o0.w = f2bf(a0.w);
                    o1.x = f2bf(a1.x); o1.y = f2bf(a1.y); o1.z = f2bf(a1.z); o1.w = f2bf(a1.w);
                    unsigned short* dst = Abuf + (size_t)c * 256;
                    *(ushort4*)(dst + hl * 4)       = o0;   // 256B contiguous/instr
                    *(ushort4*)(dst + 128 + hl * 4) = o1;   // 256B contiguous/instr
                }
            }
        }
        return;
    }

    // ---------------- mlp: 16 query rows x 256 N, LDS ping-pong ----------------
    const int m0 = blockIdx.x * 16;
    #pragma unroll
    for (int i = 0; i < 4; ++i) {
        int c = tid + i * 256;
        int row = c >> 6, kq = (c & 63) * 4;
        int gr = m0 + row; if (gr >= M) gr = M - 1;
        float4 v = *(const float4*)(Qf + (size_t)gr * 256 + kq);
        ushort4 o; o.x = f2bf(v.x); o.y = f2bf(v.y); o.z = f2bf(v.z); o.w = f2bf(v.w);
        *(ushort4*)&At[row * 264 + kq] = o;
    }
    __syncthreads();

    for (int l = 0; l < 4; ++l) {
        const unsigned short* Wl = Wb + (size_t)l * wsz;
        const float* bl = (l == 0) ? b0p : (l == 1) ? b1p : (l == 2) ? b2p : b3p;
        f32x4 acc[4] = {};
        #pragma unroll
        for (int k = 0; k < 256; k += 32) {
            bf16x8 af = *(const bf16x8*)&At[l16 * 264 + k + quad * 8];
            #pragma unroll
            for (int t = 0; t < 4; ++t) {
                int n = wid * 64 + t * 16 + l16;
                bf16x8 bfr = *(const bf16x8*)(Wl + (size_t)n * 256 + k + quad * 8);
                acc[t] = __builtin_amdgcn_mfma_f32_16x16x32_bf16(af, bfr, acc[t], 0, 0, 0);
            }
        }
        __syncthreads();
        #pragma unroll
        for (int t = 0; t < 4; ++t) {
            int n = wid * 64 + t * 16 + l16;
            float bv = bl[n];
            #pragma unroll
            for (int r = 0; r < 4; ++r) {
                int m = quad * 4 + r;
                float v = acc[t][r] + bv;
                if (l < 3) {
                    At[m * 264 + n] = f2bf(fmaxf(v, 0.f));
                } else {
                    if (m0 + m < M) outQB[(size_t)(m0 + m) * 256 + n] = f2bf(v);
                }
            }
        }
        if (l < 3) __syncthreads();
    }
}

// ---------------------------------------------------------------------------
// cell_gemm3: B-only LDS (24.3 KB -> 4 blocks/CU, all 1024 blocks resident).
// A-fragments read per-wave straight from L3-hot Abuf (16B/lane), prefetched
// one K-step ahead. No atomics, no memset.
// ---------------------------------------------------------------------------
__global__ __launch_bounds__(256, 4) void cell_gemm3(
    const unsigned short* __restrict__ Abuf,
    const unsigned short* __restrict__ QB, const int* __restrict__ qoff,
    float* __restrict__ out, int cpb, int HW, int Qstride)
{
    __shared__ unsigned short Bsm[304 * 40];   // 24320 B

    const int tid = threadIdx.x;
    const int b   = blockIdx.x / cpb;
    const int c0  = (blockIdx.x - b * cpb) * 64;
    const size_t gc0 = (size_t)b * HW + c0;
    const int q0 = qoff[b];
    int qlen = qoff[b + 1] - q0; if (qlen < 1) qlen = 1;

    const int wid = tid >> 6, lane = tid & 63, quad = lane >> 4, l16 = lane & 15;

    // A-fragment pointer: row = c0 + wid*16 + l16, col base quad*8
    const unsigned short* aptr = Abuf + (gc0 + wid * 16 + l16) * 256 + quad * 8;
    bf16x8 afA = *(const bf16x8*)aptr;          // k0 = 0 fragment
    f32x4 acc[19] = {};

    for (int k0 = 0; k0 < 256; k0 += 32) {
        // stage B: 304 q-rows x 32 k bf16, padded stride 40
        for (int c = tid; c < 1216; c += 256) {
            int row = c >> 2, kc = (c & 3) * 8;
            int qr = row < qlen ? row : qlen - 1;
            uint4 v = *(const uint4*)(QB + (size_t)(q0 + qr) * 256 + k0 + kc);
            *(uint4*)&Bsm[row * 40 + kc] = v;
        }
        int k1 = (k0 + 32) & 255;               // wraps harmlessly on last iter
        bf16x8 afB = *(const bf16x8*)(aptr + k1);
        __syncthreads();
        #pragma unroll
        for (int t = 0; t < 19; ++t) {
            bf16x8 bfr = *(const bf16x8*)&Bsm[(t * 16 + l16) * 40 + quad * 8];
            acc[t] = __builtin_amdgcn_mfma_f32_16x16x32_bf16(afA, bfr, acc[t], 0, 0, 0);
        }
        __syncthreads();
        afA = afB;
    }

    // coalesced stores; zero-fill n >= qlen (no memset of d_out needed)
    #pragma unroll
    for (int r = 0; r < 4; ++r) {
        int m = quad * 4 + r;
        float* dst = out + (gc0 + wid * 16 + m) * Qstride;
        #pragma unroll
        for (int t = 0; t < 19; ++t) {
            int nq = t * 16 + l16;
            if (nq < Qstride) dst[nq] = (nq < qlen) ? acc[t][r] : 0.f;
        }
    }
}

extern "C" void kernel_launch(void* const* d_in, const int* in_sizes, int n_in,
                              void* d_out, int out_size, void* d_ws, size_t ws_size,
                              hipStream_t stream) {
    const float* queries = (const float*)d_in[0];
    const float* FV      = (const float*)d_in[1];
    const int*   FI      = (const int*)d_in[2];
    const int*   qoff    = (const int*)d_in[3];
    const int*   wptr    = (const int*)d_in[6];
    const float* W0 = (const float*)d_in[7];
    const float* b0 = (const float*)d_in[8];
    const float* W1 = (const float*)d_in[9];
    const float* b1 = (const float*)d_in[10];
    const float* W2 = (const float*)d_in[11];
    const float* b2 = (const float*)d_in[12];
    const float* W3 = (const float*)d_in[13];
    const float* b3 = (const float*)d_in[14];
    float* out = (float*)d_out;

    const int NQe = in_sizes[0];          // 307200
    const int NQ  = NQe / 256;            // 1200
    const int NF  = in_sizes[1] / 256;    // 65536
    const int WSZ = in_sizes[7];          // 65536
    const int B   = in_sizes[3] - 1;      // 4
    const int Q   = NQ / B;               // 300
    const int HW  = out_size / (B * Q);   // 16384
    const int NC  = B * HW;               // 65536 cells
    const int cpb = HW / 64;              // 256 blocks per batch

    int* cnt   = (int*)d_ws;                                   // NC ints
    int* slots = cnt + (size_t)NC;                             // NC*16 ints
    unsigned short* wsW  = (unsigned short*)(slots + (size_t)NC * 16);  // 4*WSZ
    unsigned short* wsQB = wsW + (size_t)4 * WSZ;              // NQe bf16
    unsigned short* Abuf = wsQB + (size_t)NQe;                 // NC*256 bf16

    hipMemsetAsync(cnt, 0, (size_t)NC * sizeof(int), stream);

    const int nbBin = (NF + 255) / 256;
    const int nbW   = (4 * WSZ / 4 + 255) / 256;
    prep<<<nbBin + nbW, 256, 0, stream>>>(FI, wptr, cnt, slots,
                                          W0, W1, W2, W3, wsW, NF, HW, WSZ, nbBin);

    const int nbM = (NQ + 15) / 16;       // 75 mlp blocks
    const int nbG = 1024;                 // gather blocks (16 cells per wave)
    gather_mlp<<<nbM + nbG, 256, 0, stream>>>(
        queries, wsW, b0, b1, b2, b3, wsQB, NQ, WSZ,
        FV, cnt, slots, Abuf, NC, nbM, nbG);

    cell_gemm3<<<B * cpb, 256, 0, stream>>>(Abuf, wsQB, qoff, out, cpb, HW, Q);
}